// Round 4
// baseline (152.500 us; speedup 1.0000x reference)
//
#include <hip/hip_runtime.h>
#include <hip/hip_bf16.h>
#include <cstdint>
#include <cstddef>

// Shapes: b=8, n=8, p=q=64, x=32, y=32, d=8  -> xyd = x*256+y*8+d in [0,8192)
// Q,K,V: [bn=64][64][8192] fp32.  out: [b][p][xyd][n] fp32 (transposed).
// scores[bn][p][q] = dot_k(Q,K)/1024 -> softmax over q -> out = attn @ V.

typedef __attribute__((ext_vector_type(4))) float f32x4;
typedef __attribute__((ext_vector_type(8))) short bf16x8;
typedef __attribute__((ext_vector_type(4))) short shortx4;

__device__ __forceinline__ unsigned short f2bf(float x) {
    unsigned int u = __builtin_bit_cast(unsigned int, x);
    u += 0x7FFFu + ((u >> 16) & 1u);     // RTNE
    return (unsigned short)(u >> 16);
}

// ---------------- Kernel A: partial QK^T via bf16 MFMA ----------------
// grid (bn=64, kchunks), 256 threads = 4 waves.
// Wave w owns output quadrant (wr=w>>1, wc=w&1): 32x32 = 2x2 MFMA tiles.
// Fragments loaded straight from global (row-major, k contiguous); fp32 acc.
// partial[ch][bn][p][q]
__global__ __launch_bounds__(256) void qk_mfma_kernel(
    const float* __restrict__ Q, const float* __restrict__ K,
    float* __restrict__ partial, int clen)
{
    const int bn   = blockIdx.x;
    const int ch   = blockIdx.y;
    const int tid  = threadIdx.x;
    const int w    = tid >> 6;
    const int lane = tid & 63;
    const int wr   = w >> 1;          // p-quadrant
    const int wc   = w & 1;           // q-quadrant
    const int frow = lane & 15;       // fragment row/col within 16
    const int kg   = lane >> 4;       // 0..3 : k-subgroup of 8

    const float* Qb = Q + (size_t)bn * 64 * 8192 + (size_t)ch * clen;
    const float* Kb = K + (size_t)bn * 64 * 8192 + (size_t)ch * clen;
    const float* Aq = Qb + (size_t)(wr * 32 + frow) * 8192 + kg * 8;
    const float* Bk = Kb + (size_t)(wc * 32 + frow) * 8192 + kg * 8;

    f32x4 acc[2][2];
    #pragma unroll
    for (int mt = 0; mt < 2; ++mt)
        #pragma unroll
        for (int nt = 0; nt < 2; ++nt)
            acc[mt][nt] = (f32x4)(0.f);

    #pragma unroll 2
    for (int ks = 0; ks < clen; ks += 32) {
        bf16x8 afr[2], bfr[2];
        #pragma unroll
        for (int mt = 0; mt < 2; ++mt) {
            const float* p = Aq + (size_t)mt * 16 * 8192 + ks;
            const float4 lo = *(const float4*)p;
            const float4 hi = *(const float4*)(p + 4);
            bf16x8 f;
            f[0] = (short)f2bf(lo.x); f[1] = (short)f2bf(lo.y);
            f[2] = (short)f2bf(lo.z); f[3] = (short)f2bf(lo.w);
            f[4] = (short)f2bf(hi.x); f[5] = (short)f2bf(hi.y);
            f[6] = (short)f2bf(hi.z); f[7] = (short)f2bf(hi.w);
            afr[mt] = f;
        }
        #pragma unroll
        for (int nt = 0; nt < 2; ++nt) {
            const float* p = Bk + (size_t)nt * 16 * 8192 + ks;
            const float4 lo = *(const float4*)p;
            const float4 hi = *(const float4*)(p + 4);
            bf16x8 f;
            f[0] = (short)f2bf(lo.x); f[1] = (short)f2bf(lo.y);
            f[2] = (short)f2bf(lo.z); f[3] = (short)f2bf(lo.w);
            f[4] = (short)f2bf(hi.x); f[5] = (short)f2bf(hi.y);
            f[6] = (short)f2bf(hi.z); f[7] = (short)f2bf(hi.w);
            bfr[nt] = f;
        }
        #pragma unroll
        for (int mt = 0; mt < 2; ++mt)
            #pragma unroll
            for (int nt = 0; nt < 2; ++nt)
                acc[mt][nt] = __builtin_amdgcn_mfma_f32_16x16x32_bf16(
                    afr[mt], bfr[nt], acc[mt][nt], 0, 0, 0);
    }

    // D layout: col = lane&15 (q), row = (lane>>4)*4 + r (p)
    float* pb = partial + ((size_t)ch * 64 + bn) * 4096;
    #pragma unroll
    for (int mt = 0; mt < 2; ++mt)
        #pragma unroll
        for (int nt = 0; nt < 2; ++nt) {
            const int p0 = wr * 32 + mt * 16 + kg * 4;
            const int q0 = wc * 32 + nt * 16 + frow;
            #pragma unroll
            for (int r = 0; r < 4; ++r)
                pb[(size_t)(p0 + r) * 64 + q0] = acc[mt][nt][r];
        }
}

// ---------------- Kernel B: reduce partials + softmax (unchanged) ----------------
__global__ __launch_bounds__(256) void softmax_kernel(
    float* __restrict__ ws, const unsigned char* __restrict__ mask, int kchunks)
{
    const int row  = blockIdx.x * 4 + (threadIdx.x >> 6);
    const int q    = threadIdx.x & 63;
    float s = 0.f;
    for (int c = 0; c < kchunks; ++c)
        s += ws[((size_t)c * 4096 + row) * 64 + q];
    s *= (1.0f / 1024.0f);
    const int b = row >> 9;
    if (mask[b * 64 + q]) s = -__builtin_inff();
    float m = s;
    #pragma unroll
    for (int off = 32; off; off >>= 1) m = fmaxf(m, __shfl_xor(m, off));
    const float e = __expf(s - m);
    float sum = e;
    #pragma unroll
    for (int off = 32; off; off >>= 1) sum += __shfl_xor(sum, off);
    ws[(size_t)row * 64 + q] = e / sum;
}

// ---------------- Kernel C: PV via bf16 MFMA (unchanged, proven) ----------------
__global__ __launch_bounds__(512, 2) void pv_mfma_kernel(
    const float* __restrict__ V, const float* __restrict__ attn,
    float* __restrict__ out)
{
    __shared__ unsigned char smem[65536];   // phase 1: vt[8][64][64] bf16; phase 2: ob fp32

    const int b     = blockIdx.y;
    const int chunk = blockIdx.x;
    const int tid   = threadIdx.x;
    const int w     = tid >> 6;           // wave = n
    const int lane  = tid & 63;

    const float* Vb = V    + (size_t)(b * 8 + w) * 64 * 8192 + (size_t)chunk * 64;
    const float* Ab = attn + (size_t)(b * 8 + w) * 4096;

    unsigned short* vtn = (unsigned short*)smem + w * 4096;   // this wave's V^T tile

    // ---- stage V chunk -> LDS transposed bf16, swizzled ----
    const int c  = lane >> 2;
    const int qg = lane & 3;
    #pragma unroll
    for (int s = 0; s < 4; ++s) {
        const int q0 = s * 16 + qg * 4;
        const float4 r0 = *(const float4*)&Vb[(size_t)(q0 + 0) * 8192 + c * 4];
        const float4 r1 = *(const float4*)&Vb[(size_t)(q0 + 1) * 8192 + c * 4];
        const float4 r2 = *(const float4*)&Vb[(size_t)(q0 + 2) * 8192 + c * 4];
        const float4 r3 = *(const float4*)&Vb[(size_t)(q0 + 3) * 8192 + c * 4];
        const float v0[4] = {r0.x, r0.y, r0.z, r0.w};
        const float v1[4] = {r1.x, r1.y, r1.z, r1.w};
        const float v2[4] = {r2.x, r2.y, r2.z, r2.w};
        const float v3[4] = {r3.x, r3.y, r3.z, r3.w};
        #pragma unroll
        for (int cc = 0; cc < 4; ++cc) {
            const int row = c * 4 + cc;       // xc within chunk
            shortx4 pk;
            pk.x = (short)f2bf(v0[cc]);
            pk.y = (short)f2bf(v1[cc]);
            pk.z = (short)f2bf(v2[cc]);
            pk.w = (short)f2bf(v3[cc]);
            const int soff = row * 64 + (q0 ^ ((row & 7) << 3) ^ (((row >> 3) & 3) << 4));
            *(shortx4*)(vtn + soff) = pk;
        }
    }

    // ---- A fragments: attn rows, bf16 ----
    const int arow = lane & 15;
    const int q0a  = (lane >> 4) * 8;
    bf16x8 afrag[4][2];
    #pragma unroll
    for (int mt = 0; mt < 4; ++mt) {
        #pragma unroll
        for (int ks = 0; ks < 2; ++ks) {
            const float* ap = Ab + (mt * 16 + arow) * 64 + ks * 32 + q0a;
            const float4 lo = *(const float4*)ap;
            const float4 hi = *(const float4*)(ap + 4);
            bf16x8 f;
            f[0] = (short)f2bf(lo.x); f[1] = (short)f2bf(lo.y);
            f[2] = (short)f2bf(lo.z); f[3] = (short)f2bf(lo.w);
            f[4] = (short)f2bf(hi.x); f[5] = (short)f2bf(hi.y);
            f[6] = (short)f2bf(hi.z); f[7] = (short)f2bf(hi.w);
            afrag[mt][ks] = f;
        }
    }

    // ---- MFMA compute ----
    f32x4 acc[4][4];
    #pragma unroll
    for (int mt = 0; mt < 4; ++mt)
        #pragma unroll
        for (int nt = 0; nt < 4; ++nt)
            acc[mt][nt] = (f32x4)(0.f);

    const int bcol = lane & 15;
    const int q0b  = (lane >> 4) * 8;
    #pragma unroll
    for (int nt = 0; nt < 4; ++nt) {
        bf16x8 bfr[2];
        #pragma unroll
        for (int ks = 0; ks < 2; ++ks) {
            const int row  = nt * 16 + bcol;
            const int q0   = ks * 32 + q0b;
            const int soff = row * 64 + (q0 ^ ((row & 7) << 3) ^ (((row >> 3) & 3) << 4));
            bfr[ks] = *(const bf16x8*)(vtn + soff);
        }
        #pragma unroll
        for (int ks = 0; ks < 2; ++ks)
            #pragma unroll
            for (int mt = 0; mt < 4; ++mt)
                acc[mt][nt] = __builtin_amdgcn_mfma_f32_16x16x32_bf16(
                    afrag[mt][ks], bfr[ks], acc[mt][nt], 0, 0, 0);
    }

    // ---- store: D frags -> LDS transpose -> coalesced float4 stores ----
    float* ob = (float*)smem;          // [16 p][64 xc][9 (8n + pad)]
    const int pq = lane >> 4;
    const int pl = tid >> 5;           // 0..15 : p-row for store phase
    const int g  = tid & 31;
    #pragma unroll
    for (int mt = 0; mt < 4; ++mt) {
        __syncthreads();
        #pragma unroll
        for (int nt = 0; nt < 4; ++nt)
            #pragma unroll
            for (int r = 0; r < 4; ++r) {
                const int prow = pq * 4 + r;
                const int xc   = nt * 16 + (lane & 15);
                ob[prow * 576 + xc * 9 + w] = acc[mt][nt][r];
            }
        __syncthreads();
        float* orow = out + (size_t)b * 4194304 + (size_t)(mt * 16 + pl) * 65536
                          + (size_t)chunk * 512;
        #pragma unroll
        for (int u = 0; u < 4; ++u) {
            const int f0 = g * 4 + u * 128;
            float4 vv;
            vv.x = ob[pl * 576 + ((f0 + 0) >> 3) * 9 + ((f0 + 0) & 7)];
            vv.y = ob[pl * 576 + ((f0 + 1) >> 3) * 9 + ((f0 + 1) & 7)];
            vv.z = ob[pl * 576 + ((f0 + 2) >> 3) * 9 + ((f0 + 2) & 7)];
            vv.w = ob[pl * 576 + ((f0 + 3) >> 3) * 9 + ((f0 + 3) & 7)];
            *(float4*)&orow[f0] = vv;
        }
    }
}

extern "C" void kernel_launch(void* const* d_in, const int* in_sizes, int n_in,
                              void* d_out, int out_size, void* d_ws, size_t ws_size,
                              hipStream_t stream)
{
    const float* Q = (const float*)d_in[0];
    const float* K = (const float*)d_in[1];
    const float* V = (const float*)d_in[2];
    const unsigned char* mask = (const unsigned char*)d_in[3];
    float* out = (float*)d_out;
    float* ws  = (float*)d_ws;

    int kchunks = 16;
    while (kchunks > 1 &&
           (size_t)kchunks * 4096 * 64 * sizeof(float) > ws_size)
        kchunks >>= 1;
    const int clen = 8192 / kchunks;

    qk_mfma_kernel<<<dim3(64, kchunks), 256, 0, stream>>>(Q, K, ws, clen);
    softmax_kernel<<<1024, 256, 0, stream>>>(ws, mask, kchunks);
    pv_mfma_kernel<<<dim3(128, 8), 512, 0, stream>>>(V, ws, out);
}

// Round 5
// 142.285 us; speedup vs baseline: 1.0718x; 1.0718x over previous
//
#include <hip/hip_runtime.h>
#include <hip/hip_bf16.h>
#include <cstdint>
#include <cstddef>

// Shapes: b=8, n=8, p=q=64, x=32, y=32, d=8  -> xyd = x*256+y*8+d in [0,8192)
// Q,K,V: [bn=64][64][8192] fp32.  out: [b][p][xyd][n] fp32 (transposed).
// scores[bn][p][q] = dot_k(Q,K)/1024 -> softmax over q -> out = attn @ V.

typedef __attribute__((ext_vector_type(4))) float f32x4;
typedef __attribute__((ext_vector_type(8))) short bf16x8;
typedef __attribute__((ext_vector_type(4))) short shortx4;

__device__ __forceinline__ unsigned short f2bf(float x) {
    unsigned int u = __builtin_bit_cast(unsigned int, x);
    u += 0x7FFFu + ((u >> 16) & 1u);     // RTNE
    return (unsigned short)(u >> 16);
}

__device__ __forceinline__ bf16x8 pack8(float4 lo, float4 hi) {
    bf16x8 f;
    f[0] = (short)f2bf(lo.x); f[1] = (short)f2bf(lo.y);
    f[2] = (short)f2bf(lo.z); f[3] = (short)f2bf(lo.w);
    f[4] = (short)f2bf(hi.x); f[5] = (short)f2bf(hi.y);
    f[6] = (short)f2bf(hi.z); f[7] = (short)f2bf(hi.w);
    return f;
}

// ---------------- Kernel A: partial QK^T via bf16 MFMA, 2-deep pipeline ----
// grid (bn=64, kchunks), 256 threads = 4 waves; wave owns a 32x32 quadrant.
// partial[ch][bn][p][q]
__global__ __launch_bounds__(256, 4) void qk_mfma_kernel(
    const float* __restrict__ Q, const float* __restrict__ K,
    float* __restrict__ partial, int clen)
{
    const int bn   = blockIdx.x;
    const int ch   = blockIdx.y;
    const int tid  = threadIdx.x;
    const int w    = tid >> 6;
    const int lane = tid & 63;
    const int wr   = w >> 1;          // p-quadrant
    const int wc   = w & 1;           // q-quadrant
    const int frow = lane & 15;       // fragment row within 16
    const int kg   = lane >> 4;       // 0..3 : k-subgroup of 8

    const float* Qb = Q + (size_t)bn * 64 * 8192 + (size_t)ch * clen;
    const float* Kb = K + (size_t)bn * 64 * 8192 + (size_t)ch * clen;
    const float* Aq = Qb + (size_t)(wr * 32 + frow) * 8192 + kg * 8;
    const float* Bk = Kb + (size_t)(wc * 32 + frow) * 8192 + kg * 8;

    const int nsteps = clen >> 5;     // k-steps of 32

    f32x4 acc[2][2];
    #pragma unroll
    for (int mt = 0; mt < 2; ++mt)
        #pragma unroll
        for (int nt = 0; nt < 2; ++nt)
            acc[mt][nt] = (f32x4)(0.f);

#define LOADSTEP(buf, stp) do {                                              \
        const int _s  = (stp);                                               \
        const int _ks = (_s < nsteps ? _s : nsteps - 1) * 32;                \
        buf[0] = *(const float4*)(Aq + _ks);                                 \
        buf[1] = *(const float4*)(Aq + _ks + 4);                             \
        buf[2] = *(const float4*)(Aq + 16 * 8192 + _ks);                     \
        buf[3] = *(const float4*)(Aq + 16 * 8192 + _ks + 4);                 \
        buf[4] = *(const float4*)(Bk + _ks);                                 \
        buf[5] = *(const float4*)(Bk + _ks + 4);                             \
        buf[6] = *(const float4*)(Bk + 16 * 8192 + _ks);                     \
        buf[7] = *(const float4*)(Bk + 16 * 8192 + _ks + 4);                 \
    } while (0)

#define COMPUTESTEP(buf) do {                                                \
        const bf16x8 a0 = pack8(buf[0], buf[1]);                             \
        const bf16x8 a1 = pack8(buf[2], buf[3]);                             \
        const bf16x8 b0 = pack8(buf[4], buf[5]);                             \
        const bf16x8 b1 = pack8(buf[6], buf[7]);                             \
        acc[0][0] = __builtin_amdgcn_mfma_f32_16x16x32_bf16(a0, b0, acc[0][0], 0, 0, 0); \
        acc[0][1] = __builtin_amdgcn_mfma_f32_16x16x32_bf16(a0, b1, acc[0][1], 0, 0, 0); \
        acc[1][0] = __builtin_amdgcn_mfma_f32_16x16x32_bf16(a1, b0, acc[1][0], 0, 0, 0); \
        acc[1][1] = __builtin_amdgcn_mfma_f32_16x16x32_bf16(a1, b1, acc[1][1], 0, 0, 0); \
    } while (0)

    float4 bufA[8], bufB[8];
    LOADSTEP(bufA, 0);
    LOADSTEP(bufB, 1);
    #pragma unroll 1
    for (int s = 0; s < nsteps; s += 2) {
        COMPUTESTEP(bufA);
        LOADSTEP(bufA, s + 2);
        COMPUTESTEP(bufB);
        LOADSTEP(bufB, s + 3);
    }
#undef LOADSTEP
#undef COMPUTESTEP

    // D layout: col = lane&15 (q), row = (lane>>4)*4 + r (p)
    float* pb = partial + ((size_t)ch * 64 + bn) * 4096;
    #pragma unroll
    for (int mt = 0; mt < 2; ++mt)
        #pragma unroll
        for (int nt = 0; nt < 2; ++nt) {
            const int p0 = wr * 32 + mt * 16 + kg * 4;
            const int q0 = wc * 32 + nt * 16 + frow;
            #pragma unroll
            for (int r = 0; r < 4; ++r)
                pb[(size_t)(p0 + r) * 64 + q0] = acc[mt][nt][r];
        }
}

// ---------------- Kernel B: reduce partials + softmax (unchanged) ----------------
__global__ __launch_bounds__(256) void softmax_kernel(
    float* __restrict__ ws, const unsigned char* __restrict__ mask, int kchunks)
{
    const int row  = blockIdx.x * 4 + (threadIdx.x >> 6);
    const int q    = threadIdx.x & 63;
    float s = 0.f;
    for (int c = 0; c < kchunks; ++c)
        s += ws[((size_t)c * 4096 + row) * 64 + q];
    s *= (1.0f / 1024.0f);
    const int b = row >> 9;
    if (mask[b * 64 + q]) s = -__builtin_inff();
    float m = s;
    #pragma unroll
    for (int off = 32; off; off >>= 1) m = fmaxf(m, __shfl_xor(m, off));
    const float e = __expf(s - m);
    float sum = e;
    #pragma unroll
    for (int off = 32; off; off >>= 1) sum += __shfl_xor(sum, off);
    ws[(size_t)row * 64 + q] = e / sum;
}

// ---------------- Kernel C: PV via bf16 MFMA (unchanged, proven) ----------------
__global__ __launch_bounds__(512, 2) void pv_mfma_kernel(
    const float* __restrict__ V, const float* __restrict__ attn,
    float* __restrict__ out)
{
    __shared__ unsigned char smem[65536];   // phase 1: vt[8][64][64] bf16; phase 2: ob fp32

    const int b     = blockIdx.y;
    const int chunk = blockIdx.x;
    const int tid   = threadIdx.x;
    const int w     = tid >> 6;           // wave = n
    const int lane  = tid & 63;

    const float* Vb = V    + (size_t)(b * 8 + w) * 64 * 8192 + (size_t)chunk * 64;
    const float* Ab = attn + (size_t)(b * 8 + w) * 4096;

    unsigned short* vtn = (unsigned short*)smem + w * 4096;   // this wave's V^T tile

    // ---- stage V chunk -> LDS transposed bf16, swizzled ----
    const int c  = lane >> 2;
    const int qg = lane & 3;
    #pragma unroll
    for (int s = 0; s < 4; ++s) {
        const int q0 = s * 16 + qg * 4;
        const float4 r0 = *(const float4*)&Vb[(size_t)(q0 + 0) * 8192 + c * 4];
        const float4 r1 = *(const float4*)&Vb[(size_t)(q0 + 1) * 8192 + c * 4];
        const float4 r2 = *(const float4*)&Vb[(size_t)(q0 + 2) * 8192 + c * 4];
        const float4 r3 = *(const float4*)&Vb[(size_t)(q0 + 3) * 8192 + c * 4];
        const float v0[4] = {r0.x, r0.y, r0.z, r0.w};
        const float v1[4] = {r1.x, r1.y, r1.z, r1.w};
        const float v2[4] = {r2.x, r2.y, r2.z, r2.w};
        const float v3[4] = {r3.x, r3.y, r3.z, r3.w};
        #pragma unroll
        for (int cc = 0; cc < 4; ++cc) {
            const int row = c * 4 + cc;       // xc within chunk
            shortx4 pk;
            pk.x = (short)f2bf(v0[cc]);
            pk.y = (short)f2bf(v1[cc]);
            pk.z = (short)f2bf(v2[cc]);
            pk.w = (short)f2bf(v3[cc]);
            const int soff = row * 64 + (q0 ^ ((row & 7) << 3) ^ (((row >> 3) & 3) << 4));
            *(shortx4*)(vtn + soff) = pk;
        }
    }

    // ---- A fragments: attn rows, bf16 ----
    const int arow = lane & 15;
    const int q0a  = (lane >> 4) * 8;
    bf16x8 afrag[4][2];
    #pragma unroll
    for (int mt = 0; mt < 4; ++mt) {
        #pragma unroll
        for (int ks = 0; ks < 2; ++ks) {
            const float* ap = Ab + (mt * 16 + arow) * 64 + ks * 32 + q0a;
            const float4 lo = *(const float4*)ap;
            const float4 hi = *(const float4*)(ap + 4);
            afrag[mt][ks] = pack8(lo, hi);
        }
    }

    // ---- MFMA compute ----
    f32x4 acc[4][4];
    #pragma unroll
    for (int mt = 0; mt < 4; ++mt)
        #pragma unroll
        for (int nt = 0; nt < 4; ++nt)
            acc[mt][nt] = (f32x4)(0.f);

    const int bcol = lane & 15;
    const int q0b  = (lane >> 4) * 8;
    #pragma unroll
    for (int nt = 0; nt < 4; ++nt) {
        bf16x8 bfr[2];
        #pragma unroll
        for (int ks = 0; ks < 2; ++ks) {
            const int row  = nt * 16 + bcol;
            const int q0   = ks * 32 + q0b;
            const int soff = row * 64 + (q0 ^ ((row & 7) << 3) ^ (((row >> 3) & 3) << 4));
            bfr[ks] = *(const bf16x8*)(vtn + soff);
        }
        #pragma unroll
        for (int ks = 0; ks < 2; ++ks)
            #pragma unroll
            for (int mt = 0; mt < 4; ++mt)
                acc[mt][nt] = __builtin_amdgcn_mfma_f32_16x16x32_bf16(
                    afrag[mt][ks], bfr[ks], acc[mt][nt], 0, 0, 0);
    }

    // ---- store: D frags -> LDS transpose -> coalesced float4 stores ----
    float* ob = (float*)smem;          // [16 p][64 xc][9 (8n + pad)]
    const int pq = lane >> 4;
    const int pl = tid >> 5;           // 0..15 : p-row for store phase
    const int g  = tid & 31;
    #pragma unroll
    for (int mt = 0; mt < 4; ++mt) {
        __syncthreads();
        #pragma unroll
        for (int nt = 0; nt < 4; ++nt)
            #pragma unroll
            for (int r = 0; r < 4; ++r) {
                const int prow = pq * 4 + r;
                const int xc   = nt * 16 + (lane & 15);
                ob[prow * 576 + xc * 9 + w] = acc[mt][nt][r];
            }
        __syncthreads();
        float* orow = out + (size_t)b * 4194304 + (size_t)(mt * 16 + pl) * 65536
                          + (size_t)chunk * 512;
        #pragma unroll
        for (int u = 0; u < 4; ++u) {
            const int f0 = g * 4 + u * 128;
            float4 vv;
            vv.x = ob[pl * 576 + ((f0 + 0) >> 3) * 9 + ((f0 + 0) & 7)];
            vv.y = ob[pl * 576 + ((f0 + 1) >> 3) * 9 + ((f0 + 1) & 7)];
            vv.z = ob[pl * 576 + ((f0 + 2) >> 3) * 9 + ((f0 + 2) & 7)];
            vv.w = ob[pl * 576 + ((f0 + 3) >> 3) * 9 + ((f0 + 3) & 7)];
            *(float4*)&orow[f0] = vv;
        }
    }
}

extern "C" void kernel_launch(void* const* d_in, const int* in_sizes, int n_in,
                              void* d_out, int out_size, void* d_ws, size_t ws_size,
                              hipStream_t stream)
{
    const float* Q = (const float*)d_in[0];
    const float* K = (const float*)d_in[1];
    const float* V = (const float*)d_in[2];
    const unsigned char* mask = (const unsigned char*)d_in[3];
    float* out = (float*)d_out;
    float* ws  = (float*)d_ws;

    int kchunks = 16;
    while (kchunks > 1 &&
           (size_t)kchunks * 4096 * 64 * sizeof(float) > ws_size)
        kchunks >>= 1;
    const int clen = 8192 / kchunks;

    qk_mfma_kernel<<<dim3(64, kchunks), 256, 0, stream>>>(Q, K, ws, clen);
    softmax_kernel<<<1024, 256, 0, stream>>>(ws, mask, kchunks);
    pv_mfma_kernel<<<dim3(128, 8), 512, 0, stream>>>(V, ws, out);
}